// Round 8
// baseline (8331.553 us; speedup 1.0000x reference)
//
#include <hip/hip_runtime.h>
#include <math.h>

#define B_ 8
#define N_ 16384
#define M_ 4096
#define D_ 512
#define TPB 1024
#define PPT 16          // N_ / TPB points per thread

#define FEAT_SZ (B_ * M_ * D_)          // 16777216
#define COFF FEAT_SZ                    // coords_out
#define TOFF (FEAT_SZ + 2 * B_ * M_)    // times_out
#define POFF (TOFF + B_ * M_)           // pol_out

#define R16(F) F(0) F(1) F(2) F(3) F(4) F(5) F(6) F(7) \
               F(8) F(9) F(10) F(11) F(12) F(13) F(14) F(15)

// ---------------------------------------------------------------------------
// Kernel 1: farthest point sampling, one block per batch.
//
// Bit-exact chain (verified rounds 2-7): d2 = fma(dz,dz, fma(dx,dx, dy*dy));
// s = sqrt_rn(fadd_rn(d2, 1e-8)). Min tracked in d2 domain (commutes with the
// monotone rounded sqrt chain); argmax in s-domain via one sqrt of the thread
// max + guarded ulp-window fixup for sqrt-collapsed ties; cross-thread argmax
// via packed u64 (s_bits<<32 | N-1-idx) max-reduce (first-index tie-break =
// jnp.argmax semantics).
//
// Storage (round-8 redesign): rounds 3-7 proved the register allocator will
// NOT keep the 64-float per-thread point set resident (VGPR pinned ~52,
// ~196KB/iter re-streamed from L2; asm pins and occupancy attributes all
// failed). So the point coords now live in LDS (float2[16384] = 128 KiB of
// the 160 KiB budget) — read each iteration via conflict-free ds_read_b64
// (stride-1 float2 = 2 lanes/bank = free). Only times + d2-mins (32 named
// floats) stay per-thread: nothing left for the allocator to spill. The
// 128KiB LDS also forces 1 block/CU, aligning the compiler's occupancy
// heuristic (4 waves/EU) with the launch shape.
// ---------------------------------------------------------------------------
__global__ __launch_bounds__(TPB)
__attribute__((amdgpu_waves_per_eu(4, 4)))
void fps_kernel(
    const float* __restrict__ coords, const float* __restrict__ times,
    int* __restrict__ idx_out)
{
    const int b = blockIdx.x;
    const int t = threadIdx.x;
    const float* cb = coords + (size_t)b * N_ * 2;
    const float* tb = times + (size_t)b * N_;

    __shared__ float2 cxy[N_];                  // 128 KiB point coords
    __shared__ unsigned long long red[2][16];   // per-wave keys, parity dbuf

#define DECLV(i) float pt##i, m##i;
    R16(DECLV)
#undef DECLV

    // stage coords into LDS; times + mins into named registers
#define LOADV(i) { const int gi = (i) * TPB + t;                              \
        const float2 c2 = *(const float2*)(cb + 2 * (size_t)gi);              \
        cxy[gi] = c2; pt##i = tb[gi]; m##i = INFINITY; }
    R16(LOADV)
#undef LOADV

    // discourage rematerialization of the time loads inside the loop
#define PINV(i) asm("" : "+v"(pt##i));
    R16(PINV)
#undef PINV

    if (t == 0) idx_out[b * M_] = 0;            // deterministic seed point
    float lx = cb[0], ly = cb[1], lt = tb[0];
    __syncthreads();

    const int wave = t >> 6;
    const int lane = t & 63;

    for (int k = 1; k < M_; ++k) {
        float bm = -INFINITY;
        int   bj = 0;

        // min-update in d2 domain + first-occurrence thread argmax over m
#define UPDV(i) {                                                             \
        const float2 c2 = cxy[(i) * TPB + t];                                 \
        const float dx = c2.x - lx;                                           \
        const float dy = c2.y - ly;                                           \
        const float dz = pt##i - lt;                                          \
        const float d2 = __fmaf_rn(dz, dz, __fmaf_rn(dx, dx,                  \
                                                     __fmul_rn(dy, dy)));     \
        m##i = fminf(m##i, d2);                                               \
        if (m##i > bm) { bm = m##i; bj = (i); } }
        R16(UPDV)
#undef UPDV

        const float s_best = __fsqrt_rn(__fadd_rn(bm, 1e-8f));

        // s-tie fixup guard: slots within 32 ulps of bm could share s_best
        const unsigned bmu = __float_as_uint(bm);
        const float thresh = __uint_as_float(bmu >= 32u ? bmu - 32u : 0u);
        float cnt = 0.f;
#define CNTV(i) cnt += (m##i >= thresh) ? 1.0f : 0.0f;
        R16(CNTV)
#undef CNTV

        int fj = bj;
        if (cnt > 1.5f) {      // rare: verify candidates, take min slot index
#define FIXV(i) if (m##i >= thresh) {                                         \
            const float si = __fsqrt_rn(__fadd_rn(m##i, 1e-8f));              \
            if (si == s_best && (i) < fj) fj = (i); }
            R16(FIXV)
#undef FIXV
        }

        // pack: max s wins; tie -> max (N-1-idx) = min idx (jnp.argmax first-hit)
        unsigned long long key =
            ((unsigned long long)__float_as_uint(s_best) << 32) |
            (unsigned)(N_ - 1 - (fj * TPB + t));

        // wave (64-lane) max-reduce of the packed key
#pragma unroll
        for (int off = 1; off < 64; off <<= 1) {
            unsigned long long ok = __shfl_xor(key, off);
            if (ok > key) key = ok;
        }
        if (lane == 0) red[k & 1][wave] = key;
        __syncthreads();

        // all threads redundantly scan the 16 wave keys (broadcast reads)
        unsigned long long wk = red[k & 1][0];
#pragma unroll
        for (int w = 1; w < 16; ++w) {
            const unsigned long long ok = red[k & 1][w];
            if (ok > wk) wk = ok;
        }
        const int gi = N_ - 1 - (int)(unsigned)(wk & 0xffffffffu);
        if (t == 0) idx_out[b * M_ + k] = gi;
        // winner's coords from LDS broadcast; time via L1-hot global broadcast
        const float2 wv = cxy[gi];
        lx = wv.x; ly = wv.y; lt = tb[gi];
        // no second barrier: next iteration writes the other parity slot
    }
}

// ---------------------------------------------------------------------------
// Kernel 2: gather coords/times/polarities at sampled indices.
// ---------------------------------------------------------------------------
__global__ __launch_bounds__(256) void gather_kernel(
    const float* __restrict__ coords, const float* __restrict__ times,
    const float* __restrict__ pol, const int* __restrict__ idx,
    float* __restrict__ out)
{
    int i = blockIdx.x * 256 + threadIdx.x;       // 0 .. B_*M_-1
    if (i >= B_ * M_) return;
    int b = i >> 12;                              // / M_
    int g = b * N_ + idx[i];
    float2 c2 = *(const float2*)(coords + 2 * (size_t)g);
    *(float2*)(out + COFF + 2 * (size_t)i) = c2;
    out[TOFF + i] = times[g];
    out[POFF + i] = pol[g];
}

// ---------------------------------------------------------------------------
// Kernel 3: gathered GEMM + bias.  C[row, o] = features[src(row), :] . W[o, :]
// ---------------------------------------------------------------------------
#define BM 32
#define BN 128
#define BK 32

__global__ __launch_bounds__(256) void proj_kernel(
    const float* __restrict__ features, const float* __restrict__ W,
    const float* __restrict__ bias, const int* __restrict__ idx,
    float* __restrict__ out)
{
    __shared__ float a_lds[BK][BM + 4];
    __shared__ float w_lds[BK][BN];
    __shared__ int   src[BM];

    const int t = threadIdx.x;
    const int rowBase = blockIdx.x * BM;
    const int oBase = blockIdx.y * BN;

    if (t < BM) {
        int row = rowBase + t;
        int b = row >> 12;                // / M_
        src[t] = b * N_ + idx[row];
    }
    __syncthreads();

    const int rt = t >> 5;        // 0..7   -> rows rt*4..rt*4+3
    const int ot = t & 31;        // 0..31  -> outs ot*4..ot*4+3
    const int lr = t >> 3;        // 0..31  staging row / out
    const int lk = (t & 7) * 4;   // 0,4,...,28 staging k

    float c[4][4] = {};

    for (int kc = 0; kc < D_; kc += BK) {
        {
            float4 v = *(const float4*)(features + (size_t)src[lr] * D_ + kc + lk);
            a_lds[lk + 0][lr] = v.x; a_lds[lk + 1][lr] = v.y;
            a_lds[lk + 2][lr] = v.z; a_lds[lk + 3][lr] = v.w;
        }
#pragma unroll
        for (int p = 0; p < 4; ++p) {
            int o = p * 32 + lr;
            float4 v = *(const float4*)(W + (size_t)(oBase + o) * D_ + kc + lk);
            w_lds[lk + 0][o] = v.x; w_lds[lk + 1][o] = v.y;
            w_lds[lk + 2][o] = v.z; w_lds[lk + 3][o] = v.w;
        }
        __syncthreads();

#pragma unroll
        for (int k = 0; k < BK; ++k) {
            float4 af = *(const float4*)&a_lds[k][rt * 4];
            float4 wf = *(const float4*)&w_lds[k][ot * 4];
            float av[4] = { af.x, af.y, af.z, af.w };
            float wv[4] = { wf.x, wf.y, wf.z, wf.w };
#pragma unroll
            for (int ri = 0; ri < 4; ++ri)
#pragma unroll
                for (int oi = 0; oi < 4; ++oi)
                    c[ri][oi] = fmaf(av[ri], wv[oi], c[ri][oi]);
        }
        __syncthreads();
    }

    float4 bv = *(const float4*)(bias + oBase + ot * 4);
    float bvv[4] = { bv.x, bv.y, bv.z, bv.w };
#pragma unroll
    for (int ri = 0; ri < 4; ++ri) {
        int row = rowBase + rt * 4 + ri;
        float4 o4;
        o4.x = c[ri][0] + bvv[0];
        o4.y = c[ri][1] + bvv[1];
        o4.z = c[ri][2] + bvv[2];
        o4.w = c[ri][3] + bvv[3];
        *(float4*)(out + (size_t)row * D_ + oBase + ot * 4) = o4;
    }
}

// ---------------------------------------------------------------------------
// Kernel 4: LayerNorm in place over the proj output. One wave per row.
// ---------------------------------------------------------------------------
__global__ __launch_bounds__(256) void ln_kernel(
    float* __restrict__ out, const float* __restrict__ gamma,
    const float* __restrict__ beta)
{
    const int w = threadIdx.x >> 6;
    const int lane = threadIdx.x & 63;
    const size_t row = (size_t)blockIdx.x * 4 + w;
    float* p = out + row * D_;

    float4 v0 = *(const float4*)(p + lane * 8);
    float4 v1 = *(const float4*)(p + lane * 8 + 4);
    float x[8] = { v0.x, v0.y, v0.z, v0.w, v1.x, v1.y, v1.z, v1.w };

    float sum = 0.f;
#pragma unroll
    for (int i = 0; i < 8; ++i) sum += x[i];
#pragma unroll
    for (int off = 1; off < 64; off <<= 1) sum += __shfl_xor(sum, off);
    const float mu = sum * (1.0f / 512.0f);

    float sq = 0.f;
#pragma unroll
    for (int i = 0; i < 8; ++i) { float d = x[i] - mu; sq = fmaf(d, d, sq); }
#pragma unroll
    for (int off = 1; off < 64; off <<= 1) sq += __shfl_xor(sq, off);
    const float inv = rsqrtf(sq * (1.0f / 512.0f) + 1e-5f);

    float4 g0 = *(const float4*)(gamma + lane * 8);
    float4 g1 = *(const float4*)(gamma + lane * 8 + 4);
    float4 b0 = *(const float4*)(beta + lane * 8);
    float4 b1 = *(const float4*)(beta + lane * 8 + 4);
    float g[8] = { g0.x, g0.y, g0.z, g0.w, g1.x, g1.y, g1.z, g1.w };
    float be[8] = { b0.x, b0.y, b0.z, b0.w, b1.x, b1.y, b1.z, b1.w };

    float y[8];
#pragma unroll
    for (int i = 0; i < 8; ++i) y[i] = fmaf((x[i] - mu) * inv, g[i], be[i]);

    float4 o0 = { y[0], y[1], y[2], y[3] };
    float4 o1 = { y[4], y[5], y[6], y[7] };
    *(float4*)(p + lane * 8) = o0;
    *(float4*)(p + lane * 8 + 4) = o1;
}

// ---------------------------------------------------------------------------
extern "C" void kernel_launch(void* const* d_in, const int* in_sizes, int n_in,
                              void* d_out, int out_size, void* d_ws, size_t ws_size,
                              hipStream_t stream)
{
    const float* features   = (const float*)d_in[0];
    const float* coords     = (const float*)d_in[1];
    const float* times      = (const float*)d_in[2];
    const float* polarities = (const float*)d_in[3];
    const float* W          = (const float*)d_in[4];
    const float* bias       = (const float*)d_in[5];
    const float* gamma      = (const float*)d_in[6];
    const float* beta       = (const float*)d_in[7];
    float* out = (float*)d_out;

    int* idx = (int*)d_ws;                        // B_*M_ ints = 128 KiB scratch

    fps_kernel<<<B_, TPB, 0, stream>>>(coords, times, idx);

    gather_kernel<<<(B_ * M_ + 255) / 256, 256, 0, stream>>>(
        coords, times, polarities, idx, out);

    dim3 pgrid(B_ * M_ / BM, D_ / BN);            // (1024, 4)
    proj_kernel<<<pgrid, 256, 0, stream>>>(features, W, bias, idx, out);

    ln_kernel<<<B_ * M_ / 4, 256, 0, stream>>>(out, gamma, beta);
}

// Round 9
// 7435.519 us; speedup vs baseline: 1.1205x; 1.1205x over previous
//
#include <hip/hip_runtime.h>
#include <math.h>

#define B_ 8
#define N_ 16384
#define M_ 4096
#define D_ 512
#define TPB 1024
#define PPT 16          // N_ / TPB points per thread

#define FEAT_SZ (B_ * M_ * D_)          // 16777216
#define COFF FEAT_SZ                    // coords_out
#define TOFF (FEAT_SZ + 2 * B_ * M_)    // times_out
#define POFF (TOFF + B_ * M_)           // pol_out

#define R16(F) F(0) F(1) F(2) F(3) F(4) F(5) F(6) F(7) \
               F(8) F(9) F(10) F(11) F(12) F(13) F(14) F(15)

// DPP row ctrl codes (gfx9-lineage / CDNA): row_shr:n = 0x110|n,
// row_bcast15 = 0x142, row_bcast31 = 0x143.
template <int CTRL>
__device__ __forceinline__ float dpp_max_step(float x) {
    const int y = __builtin_amdgcn_update_dpp(0, __float_as_int(x),
                                              CTRL, 0xf, 0xf, true);
    return fmaxf(x, __int_as_float(y));   // invalid lanes read 0; values > 0
}

// ---------------------------------------------------------------------------
// Kernel 1: farthest point sampling, one block per batch.
//
// Bit-exact chain (verified r2-r8): d2 = fma(dz,dz, fma(dx,dx, dy*dy));
// s = sqrt_rn(fadd_rn(d2,1e-8)). Min tracked in d2 domain (commutes with the
// monotone sqrt chain); block argmax split into VALUE phase + INDEX phase:
//
//   value: bm = max_i m_i (v_min+v_max only, no index tracking: 8 inst/pt);
//          s_local = s(bm); wave max via DPP (VALU pipe, no LDS shuffle
//          latency); lane63 -> red_s[wave]; barrier; all scan 16 floats.
//   index: only threads with s_local == s_star (winner's wave; other waves
//          skip via execz) sqrt-verify slots in a 32-ulp window of bm and
//          atomicMin 3 packed u64s (gi<<32 | {t,x,y} bits) -> min flat index
//          = jnp.argmax first-occurrence; payload rides with its gi so
//          multi-participant ties resolve consistently. barrier; all threads
//          read the winner's (x,y,t,gi) from LDS -- no dependent global load
//          on the critical path.
//
// r8 established storage location was not the bottleneck (LDS move = no
// change); this round attacks VALU issue count + the serial reduce tail.
// ---------------------------------------------------------------------------
__global__ __launch_bounds__(TPB)
__attribute__((amdgpu_waves_per_eu(4, 4)))
void fps_kernel(
    const float* __restrict__ coords, const float* __restrict__ times,
    int* __restrict__ idx_out)
{
    const int b = blockIdx.x;
    const int t = threadIdx.x;
    const float* cb = coords + (size_t)b * N_ * 2;
    const float* tb = times + (size_t)b * N_;

    __shared__ float2 cxy[N_];                        // 128 KiB point coords
    __shared__ __align__(16) float red_s[16];         // per-wave value maxima
    __shared__ unsigned long long nxt_t[2], nxt_x[2], nxt_y[2];

#define DECLV(i) float pt##i, m##i;
    R16(DECLV)
#undef DECLV

#define LOADV(i) { const int gi = (i) * TPB + t;                              \
        const float2 c2 = *(const float2*)(cb + 2 * (size_t)gi);              \
        cxy[gi] = c2; pt##i = tb[gi]; m##i = INFINITY; }
    R16(LOADV)
#undef LOADV

#define PINV(i) asm("" : "+v"(pt##i));
    R16(PINV)
#undef PINV

    if (t == 0) {
        idx_out[b * M_] = 0;                          // deterministic seed
        nxt_t[0] = nxt_x[0] = nxt_y[0] = ~0ull;
        nxt_t[1] = nxt_x[1] = nxt_y[1] = ~0ull;
    }
    float lx = cb[0], ly = cb[1], lt = tb[0];
    __syncthreads();

    const int wave = t >> 6;
    const int lane = t & 63;

    for (int k = 1; k < M_; ++k) {
        const int par = k & 1;
        float bm = -INFINITY;

        // ---- value phase: d2-min update + running max (no index tracking)
#define UPDV(i) {                                                             \
        const float2 c2 = cxy[(i) * TPB + t];                                 \
        const float dx = c2.x - lx;                                           \
        const float dy = c2.y - ly;                                           \
        const float dz = pt##i - lt;                                          \
        const float d2 = __fmaf_rn(dz, dz, __fmaf_rn(dx, dx,                  \
                                                     __fmul_rn(dy, dy)));     \
        m##i = fminf(m##i, d2);                                               \
        bm = fmaxf(bm, m##i); }
        R16(UPDV)
#undef UPDV

        const float s_local = __fsqrt_rn(__fadd_rn(bm, 1e-8f));

        // DPP wave-max (VALU pipe): lane 63 ends with the wave max
        float v = s_local;
        v = dpp_max_step<0x111>(v);   // row_shr:1
        v = dpp_max_step<0x112>(v);   // row_shr:2
        v = dpp_max_step<0x114>(v);   // row_shr:4
        v = dpp_max_step<0x118>(v);   // row_shr:8
        v = dpp_max_step<0x142>(v);   // row_bcast:15
        v = dpp_max_step<0x143>(v);   // row_bcast:31
        if (lane == 63) red_s[wave] = v;
        __syncthreads();                              // bar1

        if (t == 0) {                                 // reset other parity
            nxt_t[par ^ 1] = ~0ull;
            nxt_x[par ^ 1] = ~0ull;
            nxt_y[par ^ 1] = ~0ull;
        }

        // all threads: block max from 16 floats (vector reads + max tree)
        const float4* rp = (const float4*)red_s;
        const float4 r0 = rp[0], r1 = rp[1], r2 = rp[2], r3 = rp[3];
        const float s_star = fmaxf(
            fmaxf(fmaxf(fmaxf(r0.x, r0.y), fmaxf(r0.z, r0.w)),
                  fmaxf(fmaxf(r1.x, r1.y), fmaxf(r1.z, r1.w))),
            fmaxf(fmaxf(fmaxf(r2.x, r2.y), fmaxf(r2.z, r2.w)),
                  fmaxf(fmaxf(r3.x, r3.y), fmaxf(r3.z, r3.w))));

        // ---- index phase: winners only (execz-skipped in non-winner waves)
        if (s_local == s_star) {
            const unsigned bmu = __float_as_uint(bm);
            const float thresh = __uint_as_float(bmu >= 32u ? bmu - 32u : 0u);
            int   fgi = 0x7fffffff;
            float ft = 0.f;
#define FINDV(i) { if (m##i >= thresh) {                                      \
            const float si = __fsqrt_rn(__fadd_rn(m##i, 1e-8f));              \
            if (si == s_star) { const int g = (i) * TPB + t;                  \
                if (g < fgi) { fgi = g; ft = pt##i; } } } }
            R16(FINDV)
#undef FINDV
            const float2 cw = cxy[fgi];
            const unsigned long long hi = ((unsigned long long)(unsigned)fgi) << 32;
            atomicMin(&nxt_t[par], hi | __float_as_uint(ft));
            atomicMin(&nxt_x[par], hi | __float_as_uint(cw.x));
            atomicMin(&nxt_y[par], hi | __float_as_uint(cw.y));
        }
        __syncthreads();                              // bar2

        const unsigned long long wt = nxt_t[par];
        const unsigned long long wx = nxt_x[par];
        const unsigned long long wy = nxt_y[par];
        const int gi = (int)(wt >> 32);
        lt = __uint_as_float((unsigned)wt);
        lx = __uint_as_float((unsigned)wx);
        ly = __uint_as_float((unsigned)wy);
        if (t == 0) idx_out[b * M_ + k] = gi;
    }
}

// ---------------------------------------------------------------------------
// Kernel 2: gather coords/times/polarities at sampled indices.
// ---------------------------------------------------------------------------
__global__ __launch_bounds__(256) void gather_kernel(
    const float* __restrict__ coords, const float* __restrict__ times,
    const float* __restrict__ pol, const int* __restrict__ idx,
    float* __restrict__ out)
{
    int i = blockIdx.x * 256 + threadIdx.x;       // 0 .. B_*M_-1
    if (i >= B_ * M_) return;
    int b = i >> 12;                              // / M_
    int g = b * N_ + idx[i];
    float2 c2 = *(const float2*)(coords + 2 * (size_t)g);
    *(float2*)(out + COFF + 2 * (size_t)i) = c2;
    out[TOFF + i] = times[g];
    out[POFF + i] = pol[g];
}

// ---------------------------------------------------------------------------
// Kernel 3: gathered GEMM + bias.  C[row, o] = features[src(row), :] . W[o, :]
// ---------------------------------------------------------------------------
#define BM 32
#define BN 128
#define BK 32

__global__ __launch_bounds__(256) void proj_kernel(
    const float* __restrict__ features, const float* __restrict__ W,
    const float* __restrict__ bias, const int* __restrict__ idx,
    float* __restrict__ out)
{
    __shared__ float a_lds[BK][BM + 4];
    __shared__ float w_lds[BK][BN];
    __shared__ int   src[BM];

    const int t = threadIdx.x;
    const int rowBase = blockIdx.x * BM;
    const int oBase = blockIdx.y * BN;

    if (t < BM) {
        int row = rowBase + t;
        int b = row >> 12;                // / M_
        src[t] = b * N_ + idx[row];
    }
    __syncthreads();

    const int rt = t >> 5;        // 0..7   -> rows rt*4..rt*4+3
    const int ot = t & 31;        // 0..31  -> outs ot*4..ot*4+3
    const int lr = t >> 3;        // 0..31  staging row / out
    const int lk = (t & 7) * 4;   // 0,4,...,28 staging k

    float c[4][4] = {};

    for (int kc = 0; kc < D_; kc += BK) {
        {
            float4 v = *(const float4*)(features + (size_t)src[lr] * D_ + kc + lk);
            a_lds[lk + 0][lr] = v.x; a_lds[lk + 1][lr] = v.y;
            a_lds[lk + 2][lr] = v.z; a_lds[lk + 3][lr] = v.w;
        }
#pragma unroll
        for (int p = 0; p < 4; ++p) {
            int o = p * 32 + lr;
            float4 v = *(const float4*)(W + (size_t)(oBase + o) * D_ + kc + lk);
            w_lds[lk + 0][o] = v.x; w_lds[lk + 1][o] = v.y;
            w_lds[lk + 2][o] = v.z; w_lds[lk + 3][o] = v.w;
        }
        __syncthreads();

#pragma unroll
        for (int k = 0; k < BK; ++k) {
            float4 af = *(const float4*)&a_lds[k][rt * 4];
            float4 wf = *(const float4*)&w_lds[k][ot * 4];
            float av[4] = { af.x, af.y, af.z, af.w };
            float wv[4] = { wf.x, wf.y, wf.z, wf.w };
#pragma unroll
            for (int ri = 0; ri < 4; ++ri)
#pragma unroll
                for (int oi = 0; oi < 4; ++oi)
                    c[ri][oi] = fmaf(av[ri], wv[oi], c[ri][oi]);
        }
        __syncthreads();
    }

    float4 bv = *(const float4*)(bias + oBase + ot * 4);
    float bvv[4] = { bv.x, bv.y, bv.z, bv.w };
#pragma unroll
    for (int ri = 0; ri < 4; ++ri) {
        int row = rowBase + rt * 4 + ri;
        float4 o4;
        o4.x = c[ri][0] + bvv[0];
        o4.y = c[ri][1] + bvv[1];
        o4.z = c[ri][2] + bvv[2];
        o4.w = c[ri][3] + bvv[3];
        *(float4*)(out + (size_t)row * D_ + oBase + ot * 4) = o4;
    }
}

// ---------------------------------------------------------------------------
// Kernel 4: LayerNorm in place over the proj output. One wave per row.
// ---------------------------------------------------------------------------
__global__ __launch_bounds__(256) void ln_kernel(
    float* __restrict__ out, const float* __restrict__ gamma,
    const float* __restrict__ beta)
{
    const int w = threadIdx.x >> 6;
    const int lane = threadIdx.x & 63;
    const size_t row = (size_t)blockIdx.x * 4 + w;
    float* p = out + row * D_;

    float4 v0 = *(const float4*)(p + lane * 8);
    float4 v1 = *(const float4*)(p + lane * 8 + 4);
    float x[8] = { v0.x, v0.y, v0.z, v0.w, v1.x, v1.y, v1.z, v1.w };

    float sum = 0.f;
#pragma unroll
    for (int i = 0; i < 8; ++i) sum += x[i];
#pragma unroll
    for (int off = 1; off < 64; off <<= 1) sum += __shfl_xor(sum, off);
    const float mu = sum * (1.0f / 512.0f);

    float sq = 0.f;
#pragma unroll
    for (int i = 0; i < 8; ++i) { float d = x[i] - mu; sq = fmaf(d, d, sq); }
#pragma unroll
    for (int off = 1; off < 64; off <<= 1) sq += __shfl_xor(sq, off);
    const float inv = rsqrtf(sq * (1.0f / 512.0f) + 1e-5f);

    float4 g0 = *(const float4*)(gamma + lane * 8);
    float4 g1 = *(const float4*)(gamma + lane * 8 + 4);
    float4 b0 = *(const float4*)(beta + lane * 8);
    float4 b1 = *(const float4*)(beta + lane * 8 + 4);
    float g[8] = { g0.x, g0.y, g0.z, g0.w, g1.x, g1.y, g1.z, g1.w };
    float be[8] = { b0.x, b0.y, b0.z, b0.w, b1.x, b1.y, b1.z, b1.w };

    float y[8];
#pragma unroll
    for (int i = 0; i < 8; ++i) y[i] = fmaf((x[i] - mu) * inv, g[i], be[i]);

    float4 o0 = { y[0], y[1], y[2], y[3] };
    float4 o1 = { y[4], y[5], y[6], y[7] };
    *(float4*)(p + lane * 8) = o0;
    *(float4*)(p + lane * 8 + 4) = o1;
}

// ---------------------------------------------------------------------------
extern "C" void kernel_launch(void* const* d_in, const int* in_sizes, int n_in,
                              void* d_out, int out_size, void* d_ws, size_t ws_size,
                              hipStream_t stream)
{
    const float* features   = (const float*)d_in[0];
    const float* coords     = (const float*)d_in[1];
    const float* times      = (const float*)d_in[2];
    const float* polarities = (const float*)d_in[3];
    const float* W          = (const float*)d_in[4];
    const float* bias       = (const float*)d_in[5];
    const float* gamma      = (const float*)d_in[6];
    const float* beta       = (const float*)d_in[7];
    float* out = (float*)d_out;

    int* idx = (int*)d_ws;                        // B_*M_ ints = 128 KiB scratch

    fps_kernel<<<B_, TPB, 0, stream>>>(coords, times, idx);

    gather_kernel<<<(B_ * M_ + 255) / 256, 256, 0, stream>>>(
        coords, times, polarities, idx, out);

    dim3 pgrid(B_ * M_ / BM, D_ / BN);            // (1024, 4)
    proj_kernel<<<pgrid, 256, 0, stream>>>(features, W, bias, idx, out);

    ln_kernel<<<B_ * M_ / 4, 256, 0, stream>>>(out, gamma, beta);
}

// Round 10
// 6213.044 us; speedup vs baseline: 1.3410x; 1.1968x over previous
//
#include <hip/hip_runtime.h>
#include <math.h>

#define B_ 8
#define N_ 16384
#define M_ 4096
#define D_ 512
#define TPB 1024
#define PPT 16          // N_ / TPB points per thread

#define FEAT_SZ (B_ * M_ * D_)          // 16777216
#define COFF FEAT_SZ                    // coords_out
#define TOFF (FEAT_SZ + 2 * B_ * M_)    // times_out
#define POFF (TOFF + B_ * M_)           // pol_out

#define R16(F) F(0) F(1) F(2) F(3) F(4) F(5) F(6) F(7) \
               F(8) F(9) F(10) F(11) F(12) F(13) F(14) F(15)
// descending order: select chains end at the SMALLEST index (first occurrence)
#define R16D(F) F(15) F(14) F(13) F(12) F(11) F(10) F(9) F(8) \
                F(7) F(6) F(5) F(4) F(3) F(2) F(1) F(0)

// DPP row ctrl codes: row_shr:n = 0x110|n, row_bcast15 = 0x142, row_bcast31 = 0x143.
template <int CTRL>
__device__ __forceinline__ float dpp_max_step(float x) {
    const int y = __builtin_amdgcn_update_dpp(0, __float_as_int(x),
                                              CTRL, 0xf, 0xf, true);
    return fmaxf(x, __int_as_float(y));   // invalid lanes read 0; s values > 0
}

// ---------------------------------------------------------------------------
// Kernel 1: farthest point sampling, one block per batch.
//
// Bit-exact chain (verified r2-r9): d2 = fma(dz,dz, fma(dx,dx, dy*dy));
// s = sqrt_rn(fadd_rn(d2,1e-8)). Min in d2 domain (commutes with monotone
// sqrt chain). Value phase: bm = max_i m_i (8 inst/pt, no index tracking);
// s_local = s(bm); DPP wave max; bar1; all threads scan 16 wave maxima.
// Index phase (winner threads only, execz-skipped elsewhere):
//   common: min slot with m_i == bm exactly, descending select chain that
//           carries pt_i (no sqrts, no dynamic indexing);
//   rare (>=2 slots within 32-ulp window of bm): sqrt-verify window slots,
//           min flat index with s == s_local (sqrt-collapse ties).
//   publish: ONE LDS atomicMin of (flat<<32 | t_bits): min flat wins
//   (jnp.argmax first-occurrence), its t rides as payload.
// bar2; all threads: gi/lt from the key, lx/ly from cxy[gi] (LDS read).
// No global load and no multi-atomic serialization on the critical path
// (r9's 3-atomic + 16-sqrt winner detour was ~0.5k cy of the 4.2k cy/iter).
// ---------------------------------------------------------------------------
__global__ __launch_bounds__(TPB)
__attribute__((amdgpu_waves_per_eu(4, 4)))
void fps_kernel(
    const float* __restrict__ coords, const float* __restrict__ times,
    int* __restrict__ idx_out)
{
    const int b = blockIdx.x;
    const int t = threadIdx.x;
    const float* cb = coords + (size_t)b * N_ * 2;
    const float* tb = times + (size_t)b * N_;

    __shared__ float2 cxy[N_];                        // 128 KiB point coords
    __shared__ __align__(16) float red_s[16];         // per-wave value maxima
    __shared__ unsigned long long nxt[2];             // winner key, parity dbuf

#define DECLV(i) float pt##i, m##i;
    R16(DECLV)
#undef DECLV

#define LOADV(i) { const int gi = (i) * TPB + t;                              \
        const float2 c2 = *(const float2*)(cb + 2 * (size_t)gi);              \
        cxy[gi] = c2; pt##i = tb[gi]; m##i = INFINITY; }
    R16(LOADV)
#undef LOADV

#define PINV(i) asm("" : "+v"(pt##i));
    R16(PINV)
#undef PINV

    if (t == 0) {
        idx_out[b * M_] = 0;                          // deterministic seed
        nxt[0] = ~0ull; nxt[1] = ~0ull;
    }
    float lx = cb[0], ly = cb[1], lt = tb[0];
    __syncthreads();

    const int wave = t >> 6;
    const int lane = t & 63;

    for (int k = 1; k < M_; ++k) {
        const int par = k & 1;
        float bm = -INFINITY;

        // ---- value phase: d2-min update + running max (no index tracking)
#define UPDV(i) {                                                             \
        const float2 c2 = cxy[(i) * TPB + t];                                 \
        const float dx = c2.x - lx;                                           \
        const float dy = c2.y - ly;                                           \
        const float dz = pt##i - lt;                                          \
        const float d2 = __fmaf_rn(dz, dz, __fmaf_rn(dx, dx,                  \
                                                     __fmul_rn(dy, dy)));     \
        m##i = fminf(m##i, d2);                                               \
        bm = fmaxf(bm, m##i); }
        R16(UPDV)
#undef UPDV

        const float s_local = __fsqrt_rn(__fadd_rn(bm, 1e-8f));

        // DPP wave-max (VALU pipe): lane 63 ends with the wave max
        float v = s_local;
        v = dpp_max_step<0x111>(v);   // row_shr:1
        v = dpp_max_step<0x112>(v);   // row_shr:2
        v = dpp_max_step<0x114>(v);   // row_shr:4
        v = dpp_max_step<0x118>(v);   // row_shr:8
        v = dpp_max_step<0x142>(v);   // row_bcast:15
        v = dpp_max_step<0x143>(v);   // row_bcast:31
        if (lane == 63) red_s[wave] = v;
        __syncthreads();                              // bar1

        if (t == 0) nxt[par ^ 1] = ~0ull;             // reset other parity

        // all threads: block max from 16 floats (vector reads + max tree)
        const float4* rp = (const float4*)red_s;
        const float4 r0 = rp[0], r1 = rp[1], r2 = rp[2], r3 = rp[3];
        const float s_star = fmaxf(
            fmaxf(fmaxf(fmaxf(r0.x, r0.y), fmaxf(r0.z, r0.w)),
                  fmaxf(fmaxf(r1.x, r1.y), fmaxf(r1.z, r1.w))),
            fmaxf(fmaxf(fmaxf(r2.x, r2.y), fmaxf(r2.z, r2.w)),
                  fmaxf(fmaxf(r3.x, r3.y), fmaxf(r3.z, r3.w))));

        // ---- index phase: winners only (execz-skipped in non-winner waves)
        if (s_local == s_star) {
            // common case: min flat index with m_i == bm exactly, t rides
            int   fj = 0x7fffffff;
            float ft = 0.f;
#define SELV(i) if (m##i == bm) { fj = (i) * TPB + t; ft = pt##i; }
            R16D(SELV)
#undef SELV

            // sqrt-collapse guard: >=2 slots within 32 ulps of bm?
            const unsigned bmu = __float_as_uint(bm);
            const float thresh = __uint_as_float(bmu >= 32u ? bmu - 32u : 0u);
            float cnt = 0.f;
#define CNTV(i) cnt += (m##i >= thresh) ? 1.0f : 0.0f;
            R16(CNTV)
#undef CNTV
            if (cnt > 1.5f) {   // rare: verify window slots in s domain
#define FIXV(i) if (m##i >= thresh) {                                         \
                const float si = __fsqrt_rn(__fadd_rn(m##i, 1e-8f));          \
                if (si == s_local) { fj = (i) * TPB + t; ft = pt##i; } }
                R16D(FIXV)
#undef FIXV
            }
            atomicMin(&nxt[par],
                      (((unsigned long long)(unsigned)fj) << 32) |
                      __float_as_uint(ft));
        }
        __syncthreads();                              // bar2

        const unsigned long long wk = nxt[par];
        const int gi = (int)(wk >> 32);
        lt = __uint_as_float((unsigned)wk);
        const float2 wv = cxy[gi];                    // LDS broadcast read
        lx = wv.x; ly = wv.y;
        if (t == 0) idx_out[b * M_ + k] = gi;
    }
}

// ---------------------------------------------------------------------------
// Kernel 2: gather coords/times/polarities at sampled indices.
// ---------------------------------------------------------------------------
__global__ __launch_bounds__(256) void gather_kernel(
    const float* __restrict__ coords, const float* __restrict__ times,
    const float* __restrict__ pol, const int* __restrict__ idx,
    float* __restrict__ out)
{
    int i = blockIdx.x * 256 + threadIdx.x;       // 0 .. B_*M_-1
    if (i >= B_ * M_) return;
    int b = i >> 12;                              // / M_
    int g = b * N_ + idx[i];
    float2 c2 = *(const float2*)(coords + 2 * (size_t)g);
    *(float2*)(out + COFF + 2 * (size_t)i) = c2;
    out[TOFF + i] = times[g];
    out[POFF + i] = pol[g];
}

// ---------------------------------------------------------------------------
// Kernel 3: gathered GEMM + bias.  C[row, o] = features[src(row), :] . W[o, :]
// ---------------------------------------------------------------------------
#define BM 32
#define BN 128
#define BK 32

__global__ __launch_bounds__(256) void proj_kernel(
    const float* __restrict__ features, const float* __restrict__ W,
    const float* __restrict__ bias, const int* __restrict__ idx,
    float* __restrict__ out)
{
    __shared__ float a_lds[BK][BM + 4];
    __shared__ float w_lds[BK][BN];
    __shared__ int   src[BM];

    const int t = threadIdx.x;
    const int rowBase = blockIdx.x * BM;
    const int oBase = blockIdx.y * BN;

    if (t < BM) {
        int row = rowBase + t;
        int b = row >> 12;                // / M_
        src[t] = b * N_ + idx[row];
    }
    __syncthreads();

    const int rt = t >> 5;        // 0..7   -> rows rt*4..rt*4+3
    const int ot = t & 31;        // 0..31  -> outs ot*4..ot*4+3
    const int lr = t >> 3;        // 0..31  staging row / out
    const int lk = (t & 7) * 4;   // 0,4,...,28 staging k

    float c[4][4] = {};

    for (int kc = 0; kc < D_; kc += BK) {
        {
            float4 v = *(const float4*)(features + (size_t)src[lr] * D_ + kc + lk);
            a_lds[lk + 0][lr] = v.x; a_lds[lk + 1][lr] = v.y;
            a_lds[lk + 2][lr] = v.z; a_lds[lk + 3][lr] = v.w;
        }
#pragma unroll
        for (int p = 0; p < 4; ++p) {
            int o = p * 32 + lr;
            float4 v = *(const float4*)(W + (size_t)(oBase + o) * D_ + kc + lk);
            w_lds[lk + 0][o] = v.x; w_lds[lk + 1][o] = v.y;
            w_lds[lk + 2][o] = v.z; w_lds[lk + 3][o] = v.w;
        }
        __syncthreads();

#pragma unroll
        for (int k = 0; k < BK; ++k) {
            float4 af = *(const float4*)&a_lds[k][rt * 4];
            float4 wf = *(const float4*)&w_lds[k][ot * 4];
            float av[4] = { af.x, af.y, af.z, af.w };
            float wv[4] = { wf.x, wf.y, wf.z, wf.w };
#pragma unroll
            for (int ri = 0; ri < 4; ++ri)
#pragma unroll
                for (int oi = 0; oi < 4; ++oi)
                    c[ri][oi] = fmaf(av[ri], wv[oi], c[ri][oi]);
        }
        __syncthreads();
    }

    float4 bv = *(const float4*)(bias + oBase + ot * 4);
    float bvv[4] = { bv.x, bv.y, bv.z, bv.w };
#pragma unroll
    for (int ri = 0; ri < 4; ++ri) {
        int row = rowBase + rt * 4 + ri;
        float4 o4;
        o4.x = c[ri][0] + bvv[0];
        o4.y = c[ri][1] + bvv[1];
        o4.z = c[ri][2] + bvv[2];
        o4.w = c[ri][3] + bvv[3];
        *(float4*)(out + (size_t)row * D_ + oBase + ot * 4) = o4;
    }
}

// ---------------------------------------------------------------------------
// Kernel 4: LayerNorm in place over the proj output. One wave per row.
// ---------------------------------------------------------------------------
__global__ __launch_bounds__(256) void ln_kernel(
    float* __restrict__ out, const float* __restrict__ gamma,
    const float* __restrict__ beta)
{
    const int w = threadIdx.x >> 6;
    const int lane = threadIdx.x & 63;
    const size_t row = (size_t)blockIdx.x * 4 + w;
    float* p = out + row * D_;

    float4 v0 = *(const float4*)(p + lane * 8);
    float4 v1 = *(const float4*)(p + lane * 8 + 4);
    float x[8] = { v0.x, v0.y, v0.z, v0.w, v1.x, v1.y, v1.z, v1.w };

    float sum = 0.f;
#pragma unroll
    for (int i = 0; i < 8; ++i) sum += x[i];
#pragma unroll
    for (int off = 1; off < 64; off <<= 1) sum += __shfl_xor(sum, off);
    const float mu = sum * (1.0f / 512.0f);

    float sq = 0.f;
#pragma unroll
    for (int i = 0; i < 8; ++i) { float d = x[i] - mu; sq = fmaf(d, d, sq); }
#pragma unroll
    for (int off = 1; off < 64; off <<= 1) sq += __shfl_xor(sq, off);
    const float inv = rsqrtf(sq * (1.0f / 512.0f) + 1e-5f);

    float4 g0 = *(const float4*)(gamma + lane * 8);
    float4 g1 = *(const float4*)(gamma + lane * 8 + 4);
    float4 b0 = *(const float4*)(beta + lane * 8);
    float4 b1 = *(const float4*)(beta + lane * 8 + 4);
    float g[8] = { g0.x, g0.y, g0.z, g0.w, g1.x, g1.y, g1.z, g1.w };
    float be[8] = { b0.x, b0.y, b0.z, b0.w, b1.x, b1.y, b1.z, b1.w };

    float y[8];
#pragma unroll
    for (int i = 0; i < 8; ++i) y[i] = fmaf((x[i] - mu) * inv, g[i], be[i]);

    float4 o0 = { y[0], y[1], y[2], y[3] };
    float4 o1 = { y[4], y[5], y[6], y[7] };
    *(float4*)(p + lane * 8) = o0;
    *(float4*)(p + lane * 8 + 4) = o1;
}

// ---------------------------------------------------------------------------
extern "C" void kernel_launch(void* const* d_in, const int* in_sizes, int n_in,
                              void* d_out, int out_size, void* d_ws, size_t ws_size,
                              hipStream_t stream)
{
    const float* features   = (const float*)d_in[0];
    const float* coords     = (const float*)d_in[1];
    const float* times      = (const float*)d_in[2];
    const float* polarities = (const float*)d_in[3];
    const float* W          = (const float*)d_in[4];
    const float* bias       = (const float*)d_in[5];
    const float* gamma      = (const float*)d_in[6];
    const float* beta       = (const float*)d_in[7];
    float* out = (float*)d_out;

    int* idx = (int*)d_ws;                        // B_*M_ ints = 128 KiB scratch

    fps_kernel<<<B_, TPB, 0, stream>>>(coords, times, idx);

    gather_kernel<<<(B_ * M_ + 255) / 256, 256, 0, stream>>>(
        coords, times, polarities, idx, out);

    dim3 pgrid(B_ * M_ / BM, D_ / BN);            // (1024, 4)
    proj_kernel<<<pgrid, 256, 0, stream>>>(features, W, bias, idx, out);

    ln_kernel<<<B_ * M_ / 4, 256, 0, stream>>>(out, gamma, beta);
}